// Round 6
// baseline (533.296 us; speedup 1.0000x reference)
//
#include <hip/hip_runtime.h>
#include <hip/hip_bf16.h>

#define N_NODES 50000
#define E_EDGES 800000
#define EP_EDGES 850000   // E + N self loops
#define IN_DIM 160
#define HEADS 4
#define HID 64
#define C1 256            // HEADS*HID
#define NEG_SLOPE 0.2f
#define BN_EPS 1e-5f

typedef __attribute__((ext_vector_type(8))) short bf16x8;
typedef __attribute__((ext_vector_type(4))) float f32x4;
typedef _Float16 half2v __attribute__((ext_vector_type(2)));

union H2 { uint u; half2v h; };

__device__ __forceinline__ float b2f(ushort u) {
    return __uint_as_float(((unsigned)u) << 16);
}
__device__ __forceinline__ ushort f2b(float f) {
    __hip_bfloat16 h = __float2bfloat16(f);
    return *reinterpret_cast<ushort*>(&h);
}
__device__ __forceinline__ ushort f2h(float f) {
    _Float16 h = (_Float16)f;
    return *reinterpret_cast<ushort*>(&h);
}
__device__ __forceinline__ float lo16(uint u) { return __uint_as_float(u << 16); }
__device__ __forceinline__ float hi16(uint u) { return __uint_as_float(u & 0xffff0000u); }

// DPP-based add of a permuted copy: pure VALU pipe
template<int CTRL>
__device__ __forceinline__ float dpp_add(float p) {
    int t = __builtin_amdgcn_update_dpp(0, __float_as_int(p), CTRL, 0xf, 0xf, true);
    return p + __int_as_float(t);
}
// sum over each 8-lane group; all 8 lanes get the group total
__device__ __forceinline__ float grp8_sum(float p) {
    p = dpp_add<0xB1>(p);    // quad_perm xor1
    p = dpp_add<0x4E>(p);    // quad_perm xor2
    p = dpp_add<0x141>(p);   // row_half_mirror (xor4 within 8)
    return p;
}

// ---------------- runtime dtype detection ----------------
__global__ void detect_k(const ushort* __restrict__ xraw,
                         const int* __restrict__ eraw,
                         int* __restrict__ flags) {
    int lane = threadIdx.x;  // 64 threads
    int good = 0, nz = 0;
    for (int i = lane; i < 256; i += 64) {
        float a = fabsf(b2f(xraw[2 * i]));
        good += (a > 1e-6f && a < 1e6f) ? 1 : 0;
        nz += (eraw[2 * i + 1] != 0) ? 1 : 0;
    }
    #pragma unroll
    for (int off = 32; off > 0; off >>= 1) {
        good += __shfl_xor(good, off);
        nz += __shfl_xor(nz, off);
    }
    if (lane == 0) {
        flags[0] = (good < 192) ? 1 : 0;   // fp32 floats?
        flags[1] = (nz == 0) ? 1 : 0;      // int64 edges?
    }
}

// ---------------- canonicalize x -> bf16 (also zeroes deg) ----------------
__global__ void cvt_x_k(const void* __restrict__ src, ushort* __restrict__ dst,
                        const int* __restrict__ flags, int* __restrict__ deg) {
    int i = blockIdx.x * 256 + threadIdx.x;
    if (i < N_NODES) deg[i] = 0;
    if (i >= N_NODES * IN_DIM) return;
    dst[i] = flags[0] ? f2b(((const float*)src)[i]) : ((const ushort*)src)[i];
}

// ---------------- canonicalize 24 small param tensors -> bf16 region ----------------
struct PP { const void* p[24]; };

__global__ void cvt_params_k(PP pp, ushort* __restrict__ dst,
                             const int* __restrict__ flags) {
    const int SIZES[24] = {40960, 256, 40960, 256, 256, 256, 256, 256, 256, 256,
                           16384, 64, 16384, 64, 64, 64, 64, 64, 64, 64,
                           10240, 64, 64, 1};
    const int OFFS[24] = {0, 40960, 41216, 82176, 82432, 82688, 82944, 83200, 83456, 83712,
                          83968, 100352, 100416, 116800, 116864, 116928, 116992, 117056, 117120, 117184,
                          117248, 127488, 127552, 127616};
    int t = blockIdx.x;
    int sz = SIZES[t], off = OFFS[t];
    bool f32 = flags[0] != 0;
    const float* pf = (const float*)pp.p[t];
    const ushort* pu = (const ushort*)pp.p[t];
    for (int i = threadIdx.x; i < sz; i += blockDim.x)
        dst[off + i] = f32 ? f2b(pf[i]) : pu[i];
}

// ---------------- fp16 copies of att1/att2 for the conv kernels ----------------
__global__ void cvt_att_k(const ushort* __restrict__ att1c,
                          const ushort* __restrict__ att2c,
                          ushort* __restrict__ att1h,
                          ushort* __restrict__ att2h) {
    int i = threadIdx.x;  // 320 threads
    if (i < 256) att1h[i] = f2h(b2f(att1c[i]));
    else if (i < 320) att2h[i - 256] = f2h(b2f(att2c[i - 256]));
}

// ---------------- fused weight swizzle into MFMA B-fragment order ----------------
struct SWZ {
    const ushort* W[5];
    ushort* D[5];
    int NT[5];
    int base[5];
    int total;
};

__global__ void swz_all_k(SWZ s) {
    int idx = blockIdx.x * 256 + threadIdx.x;
    if (idx >= s.total) return;
    int seg = 0;
    #pragma unroll
    for (int k = 1; k < 5; ++k) seg += (idx >= s.base[k]) ? 1 : 0;
    int li = idx - s.base[seg];
    int NT = s.NT[seg];
    int N = NT << 4;
    int lane = li & 63;
    int ft = li >> 6;
    int kb = ft / NT, t = ft - kb * NT;
    int q = lane >> 4, m = lane & 15;
    const ushort* W = s.W[seg];
    ushort* d = s.D[seg] + (size_t)li * 8;
    #pragma unroll
    for (int j = 0; j < 8; ++j)
        d[j] = W[(size_t)(kb * 32 + q * 8 + j) * N + t * 16 + m];
}

// ---------------- CSR build (reads raw edge_index, flag-dependent stride) ----------------
__global__ void hist_k(const int* __restrict__ ei, const int* __restrict__ flags,
                       int* __restrict__ deg) {
    int e = blockIdx.x * 256 + threadIdx.x;
    if (e >= EP_EDGES) return;
    int dst;
    if (e < E_EDGES) {
        int idx = E_EDGES + e;
        dst = flags[1] ? ei[2 * idx] : ei[idx];
    } else dst = e - E_EDGES;
    atomicAdd(&deg[dst], 1);
}

__global__ __launch_bounds__(1024) void scan1_k(const int* __restrict__ deg,
                                                int* __restrict__ exc,
                                                int* __restrict__ bsum) {
    __shared__ int s[1024];
    int i = blockIdx.x * 1024 + threadIdx.x;
    int v = (i < N_NODES) ? deg[i] : 0;
    s[threadIdx.x] = v;
    __syncthreads();
    for (int off = 1; off < 1024; off <<= 1) {
        int t = (threadIdx.x >= off) ? s[threadIdx.x - off] : 0;
        __syncthreads();
        s[threadIdx.x] += t;
        __syncthreads();
    }
    if (i < N_NODES) exc[i] = s[threadIdx.x] - v;
    if (threadIdx.x == 1023) bsum[blockIdx.x] = s[1023];
}

__global__ void scan2_k(int* __restrict__ bsum, int nb) {
    int lane = threadIdx.x;  // single wave of 64
    int v = (lane < nb) ? bsum[lane] : 0;
    int orig = v;
    #pragma unroll
    for (int d = 1; d < 64; d <<= 1) {
        int t = __shfl_up(v, d);
        if (lane >= d) v += t;
    }
    if (lane < nb) bsum[lane] = v - orig;
}

__global__ void scan3_k(int* __restrict__ row_ptr, const int* __restrict__ bsum,
                        int* __restrict__ rowcur) {
    int i = blockIdx.x * 256 + threadIdx.x;
    if (i >= N_NODES) return;
    int rp = row_ptr[i] + bsum[i >> 10];
    row_ptr[i] = rp;
    rowcur[i] = rp;
    if (i == 0) row_ptr[N_NODES] = EP_EDGES;
}

__global__ void scatter_k(const int* __restrict__ ei, const int* __restrict__ flags,
                          int* __restrict__ rowcur, int* __restrict__ col) {
    int e = blockIdx.x * 256 + threadIdx.x;
    if (e >= EP_EDGES) return;
    int src, dst;
    if (e < E_EDGES) {
        if (flags[1]) { src = ei[2 * e]; dst = ei[2 * (E_EDGES + e)]; }
        else          { src = ei[e];     dst = ei[E_EDGES + e]; }
    } else { src = e - E_EDGES; dst = src; }
    int pos = atomicAdd(&rowcur[dst], 1);
    col[pos] = src;
}

// ---------------- fused layer-1 MFMA GEMM: xl1(256,fp16) + xr1(256,fp16) + xskip(64,bf16) ----------------
__global__ __launch_bounds__(256) void gemm3_k(const ushort* __restrict__ A,
                                               const ushort* __restrict__ B1,
                                               const ushort* __restrict__ B2,
                                               const ushort* __restrict__ B3,
                                               const ushort* __restrict__ bi1,
                                               const ushort* __restrict__ bi2,
                                               const ushort* __restrict__ bi3,
                                               ushort* __restrict__ o1,
                                               ushort* __restrict__ o2,
                                               ushort* __restrict__ o3,
                                               int M) {
    const int wave = threadIdx.x >> 6;
    const int lane = threadIdx.x & 63;
    const int row0 = blockIdx.x * 64 + wave * 16;
    if (row0 >= M) return;
    int arow = row0 + (lane & 15);
    if (arow >= M) arow = M - 1;
    const ushort* aptr = A + (size_t)arow * IN_DIM + (lane >> 4) * 8;
    bf16x8 af[5];
    #pragma unroll
    for (int kb = 0; kb < 5; ++kb) af[kb] = *(const bf16x8*)(aptr + kb * 32);
    const bf16x8* b1 = (const bf16x8*)B1;
    const bf16x8* b2 = (const bf16x8*)B2;
    const bf16x8* b3 = (const bf16x8*)B3;
    f32x4 aL[16] = {}, aR[16] = {}, aS[4] = {};
    #pragma unroll
    for (int kb = 0; kb < 5; ++kb) {
        #pragma unroll
        for (int t = 0; t < 16; ++t)
            aL[t] = __builtin_amdgcn_mfma_f32_16x16x32_bf16(af[kb], b1[(kb * 16 + t) * 64 + lane], aL[t], 0, 0, 0);
        #pragma unroll
        for (int t = 0; t < 16; ++t)
            aR[t] = __builtin_amdgcn_mfma_f32_16x16x32_bf16(af[kb], b2[(kb * 16 + t) * 64 + lane], aR[t], 0, 0, 0);
        #pragma unroll
        for (int t = 0; t < 4; ++t)
            aS[t] = __builtin_amdgcn_mfma_f32_16x16x32_bf16(af[kb], b3[(kb * 4 + t) * 64 + lane], aS[t], 0, 0, 0);
    }
    const int cn = lane & 15, cq = lane >> 4;
    #pragma unroll
    for (int t = 0; t < 16; ++t) {
        float bbL = b2f(bi1[t * 16 + cn]);
        float bbR = b2f(bi2[t * 16 + cn]);
        #pragma unroll
        for (int r = 0; r < 4; ++r) {
            int grow = row0 + cq * 4 + r;
            if (grow < M) {
                o1[(size_t)grow * C1 + t * 16 + cn] = f2h(aL[t][r] + bbL);
                o2[(size_t)grow * C1 + t * 16 + cn] = f2h(aR[t][r] + bbR);
            }
        }
    }
    #pragma unroll
    for (int t = 0; t < 4; ++t) {
        float bb = b2f(bi3[t * 16 + cn]);
        #pragma unroll
        for (int r = 0; r < 4; ++r) {
            int grow = row0 + cq * 4 + r;
            if (grow < M)
                o3[(size_t)grow * HID + t * 16 + cn] = f2b(aS[t][r] + bb);
        }
    }
}

// ---------------- fused layer-2 MFMA GEMM: xl2(64) + xr2(64) fp16, K=256 ----------------
__global__ __launch_bounds__(256) void gemm2_k(const ushort* __restrict__ A,
                                               const ushort* __restrict__ B1,
                                               const ushort* __restrict__ B2,
                                               const ushort* __restrict__ bi1,
                                               const ushort* __restrict__ bi2,
                                               ushort* __restrict__ o1,
                                               ushort* __restrict__ o2,
                                               int M) {
    const int wave = threadIdx.x >> 6;
    const int lane = threadIdx.x & 63;
    const int row0 = blockIdx.x * 64 + wave * 16;
    if (row0 >= M) return;
    int arow = row0 + (lane & 15);
    if (arow >= M) arow = M - 1;
    const ushort* aptr = A + (size_t)arow * C1 + (lane >> 4) * 8;
    const bf16x8* b1 = (const bf16x8*)B1;
    const bf16x8* b2 = (const bf16x8*)B2;
    f32x4 aL[4] = {}, aR[4] = {};
    #pragma unroll
    for (int kb = 0; kb < 8; ++kb) {
        bf16x8 af = *(const bf16x8*)(aptr + kb * 32);
        #pragma unroll
        for (int t = 0; t < 4; ++t)
            aL[t] = __builtin_amdgcn_mfma_f32_16x16x32_bf16(af, b1[(kb * 4 + t) * 64 + lane], aL[t], 0, 0, 0);
        #pragma unroll
        for (int t = 0; t < 4; ++t)
            aR[t] = __builtin_amdgcn_mfma_f32_16x16x32_bf16(af, b2[(kb * 4 + t) * 64 + lane], aR[t], 0, 0, 0);
    }
    const int cn = lane & 15, cq = lane >> 4;
    #pragma unroll
    for (int t = 0; t < 4; ++t) {
        float bbL = b2f(bi1[t * 16 + cn]);
        float bbR = b2f(bi2[t * 16 + cn]);
        #pragma unroll
        for (int r = 0; r < 4; ++r) {
            int grow = row0 + cq * 4 + r;
            if (grow < M) {
                o1[(size_t)grow * HID + t * 16 + cn] = f2h(aL[t][r] + bbL);
                o2[(size_t)grow * HID + t * 16 + cn] = f2h(aR[t][r] + bbR);
            }
        }
    }
}

// ---------------- conv1: fp16 pk-math, 8 edges/trip, 8 lanes/edge, 8 ch/lane ----------------
// Block = node; wave = head. logit = (0.6att)·t + (0.4att)·|t| (lrelu decomposition).
__global__ __launch_bounds__(256) void conv1_k(const ushort* __restrict__ xl,   // fp16
                                               const ushort* __restrict__ xr,   // fp16
                                               const int* __restrict__ row_ptr,
                                               const int* __restrict__ col,
                                               const ushort* __restrict__ att_h, // fp16 [256]
                                               const ushort* __restrict__ bias1, // bf16 params
                                               const ushort* __restrict__ g1,
                                               const ushort* __restrict__ b1,
                                               const ushort* __restrict__ m1,
                                               const ushort* __restrict__ v1,
                                               ushort* __restrict__ h1out) {     // bf16
    const int n = blockIdx.x;
    const int h = threadIdx.x >> 6;          // wave = head
    const int lane = threadIdx.x & 63;
    const int slot = lane >> 3;              // edge slot 0..7
    const int c = lane & 7;                  // uint4 (8ch) group
    const int off = h * 8 + c;               // uint4 index within 32-uint4 row
    const uint4* xl4 = (const uint4*)xl;
    const uint4 xru = ((const uint4*)xr)[(size_t)n * 32 + off];
    H2 xr0, xr1, xr2, xr3;
    xr0.u = xru.x; xr1.u = xru.y; xr2.u = xru.z; xr3.u = xru.w;
    const uint4 atu = ((const uint4*)att_h)[off];
    const half2v k06 = {(_Float16)0.6f, (_Float16)0.6f};
    const half2v k04 = {(_Float16)0.4f, (_Float16)0.4f};
    H2 atr; half2v a06[4], a04[4];
    atr.u = atu.x; a06[0] = atr.h * k06; a04[0] = atr.h * k04;
    atr.u = atu.y; a06[1] = atr.h * k06; a04[1] = atr.h * k04;
    atr.u = atu.z; a06[2] = atr.h * k06; a04[2] = atr.h * k04;
    atr.u = atu.w; a06[3] = atr.h * k06; a04[3] = atr.h * k04;
    const int e0 = row_ptr[n], e1 = row_ptr[n + 1];
    H2 acc0, acc1, acc2, acc3;
    acc0.u = 0; acc1.u = 0; acc2.u = 0; acc3.u = 0;
    float den = 0.f;
    int j0 = e0 + slot;
    int s = col[j0 < e1 ? j0 : e1 - 1];
    uint4 xu = xl4[(size_t)s * 32 + off];
    for (int i = e0; i < e1; i += 8) {
        const int jn = i + 8 + slot;
        const int sn = col[jn < e1 ? jn : e1 - 1];
        const uint4 xun = xl4[(size_t)sn * 32 + off];
        const bool valid = (i + slot) < e1;
        H2 x0, x1, x2, x3;
        x0.u = xu.x; x1.u = xu.y; x2.u = xu.z; x3.u = xu.w;
        H2 t0, t1, t2, t3, u0, u1, u2, u3;
        t0.h = x0.h + xr0.h; u0.u = t0.u & 0x7fff7fffu;
        t1.h = x1.h + xr1.h; u1.u = t1.u & 0x7fff7fffu;
        t2.h = x2.h + xr2.h; u2.u = t2.u & 0x7fff7fffu;
        t3.h = x3.h + xr3.h; u3.u = t3.u & 0x7fff7fffu;
        float p06 = __builtin_amdgcn_fdot2(t0.h, a06[0], 0.f, false);
        float p04 = __builtin_amdgcn_fdot2(u0.h, a04[0], 0.f, false);
        p06 = __builtin_amdgcn_fdot2(t1.h, a06[1], p06, false);
        p04 = __builtin_amdgcn_fdot2(u1.h, a04[1], p04, false);
        p06 = __builtin_amdgcn_fdot2(t2.h, a06[2], p06, false);
        p04 = __builtin_amdgcn_fdot2(u2.h, a04[2], p04, false);
        p06 = __builtin_amdgcn_fdot2(t3.h, a06[3], p06, false);
        p04 = __builtin_amdgcn_fdot2(u3.h, a04[3], p04, false);
        float p = grp8_sum(p06 + p04);
        const float w = valid ? __expf(fminf(p, 60.f)) : 0.f;
        const _Float16 wh = (_Float16)w;
        const half2v w2 = {wh, wh};
        acc0.h += w2 * x0.h;
        acc1.h += w2 * x1.h;
        acc2.h += w2 * x2.h;
        acc3.h += w2 * x3.h;
        den += w;
        xu = xun;
    }
    // unpack acc to fp32, reduce across the 8 edge slots (xor 8,16,32)
    float af[8];
    af[0] = (float)acc0.h[0]; af[1] = (float)acc0.h[1];
    af[2] = (float)acc1.h[0]; af[3] = (float)acc1.h[1];
    af[4] = (float)acc2.h[0]; af[5] = (float)acc2.h[1];
    af[6] = (float)acc3.h[0]; af[7] = (float)acc3.h[1];
    #pragma unroll
    for (int d = 8; d < 64; d <<= 1) {
        #pragma unroll
        for (int k = 0; k < 8; ++k) af[k] += __shfl_xor(af[k], d);
        den += __shfl_xor(den, d);
    }
    if (lane < 8) {
        const int pi = h * 8 + lane;  // uint4 index into 32-uint4 param row
        const float inv = 1.f / den;
        const uint4 biu = ((const uint4*)bias1)[pi];
        const uint4 gu  = ((const uint4*)g1)[pi];
        const uint4 bu  = ((const uint4*)b1)[pi];
        const uint4 mu  = ((const uint4*)m1)[pi];
        const uint4 vu  = ((const uint4*)v1)[pi];
        const uint bi_[8] = {biu.x, biu.x, biu.y, biu.y, biu.z, biu.z, biu.w, biu.w};
        const uint g_[8]  = {gu.x, gu.x, gu.y, gu.y, gu.z, gu.z, gu.w, gu.w};
        const uint b_[8]  = {bu.x, bu.x, bu.y, bu.y, bu.z, bu.z, bu.w, bu.w};
        const uint m_[8]  = {mu.x, mu.x, mu.y, mu.y, mu.z, mu.z, mu.w, mu.w};
        const uint v_[8]  = {vu.x, vu.x, vu.y, vu.y, vu.z, vu.z, vu.w, vu.w};
        ushort ov[8];
        #pragma unroll
        for (int k = 0; k < 8; ++k) {
            float bb = (k & 1) ? hi16(bi_[k]) : lo16(bi_[k]);
            float gg = (k & 1) ? hi16(g_[k])  : lo16(g_[k]);
            float bnb = (k & 1) ? hi16(b_[k]) : lo16(b_[k]);
            float mm = (k & 1) ? hi16(m_[k])  : lo16(m_[k]);
            float vv = (k & 1) ? hi16(v_[k])  : lo16(v_[k]);
            float o = fmaf(af[k], inv, bb);
            float sc = gg * rsqrtf(vv + BN_EPS);
            ov[k] = f2b(fmaxf((o - mm) * sc + bnb, 0.f));
        }
        uint4 ou;
        ou.x = (uint)ov[0] | ((uint)ov[1] << 16);
        ou.y = (uint)ov[2] | ((uint)ov[3] << 16);
        ou.z = (uint)ov[4] | ((uint)ov[5] << 16);
        ou.w = (uint)ov[6] | ((uint)ov[7] << 16);
        ((uint4*)h1out)[(size_t)n * 32 + pi] = ou;
    }
}

// ---------------- conv2 + BN2 + relu + skip + output linear ----------------
// Wave = node (4/block); 8 edges/trip, 8 lanes/edge, 8 ch/lane, fp16 pk-math.
__global__ __launch_bounds__(256) void conv2_k(const ushort* __restrict__ xl,   // fp16
                                               const ushort* __restrict__ xr,   // fp16
                                               const ushort* __restrict__ xskip,// bf16
                                               const int* __restrict__ row_ptr,
                                               const int* __restrict__ col,
                                               const ushort* __restrict__ att_h,// fp16 [64]
                                               const ushort* __restrict__ bias2,
                                               const ushort* __restrict__ g2,
                                               const ushort* __restrict__ bb2,
                                               const ushort* __restrict__ m2,
                                               const ushort* __restrict__ v2,
                                               const ushort* __restrict__ Wo,
                                               const ushort* __restrict__ bo,
                                               void* __restrict__ out,
                                               const int* __restrict__ flags) {
    const int n = blockIdx.x * 4 + (threadIdx.x >> 6);
    if (n >= N_NODES) return;
    const int lane = threadIdx.x & 63;
    const int slot = lane >> 3;
    const int c = lane & 7;                  // uint4 index within 8-uint4 row
    const uint4* xl4 = (const uint4*)xl;
    const uint4 xru = ((const uint4*)xr)[(size_t)n * 8 + c];
    H2 xr0, xr1, xr2, xr3;
    xr0.u = xru.x; xr1.u = xru.y; xr2.u = xru.z; xr3.u = xru.w;
    const uint4 atu = ((const uint4*)att_h)[c];
    const half2v k06 = {(_Float16)0.6f, (_Float16)0.6f};
    const half2v k04 = {(_Float16)0.4f, (_Float16)0.4f};
    H2 atr; half2v a06[4], a04[4];
    atr.u = atu.x; a06[0] = atr.h * k06; a04[0] = atr.h * k04;
    atr.u = atu.y; a06[1] = atr.h * k06; a04[1] = atr.h * k04;
    atr.u = atu.z; a06[2] = atr.h * k06; a04[2] = atr.h * k04;
    atr.u = atu.w; a06[3] = atr.h * k06; a04[3] = atr.h * k04;
    const int e0 = row_ptr[n], e1 = row_ptr[n + 1];
    H2 acc0, acc1, acc2, acc3;
    acc0.u = 0; acc1.u = 0; acc2.u = 0; acc3.u = 0;
    float den = 0.f;
    int j0 = e0 + slot;
    int s = col[j0 < e1 ? j0 : e1 - 1];
    uint4 xu = xl4[(size_t)s * 8 + c];
    for (int i = e0; i < e1; i += 8) {
        const int jn = i + 8 + slot;
        const int sn = col[jn < e1 ? jn : e1 - 1];
        const uint4 xun = xl4[(size_t)sn * 8 + c];
        const bool valid = (i + slot) < e1;
        H2 x0, x1, x2, x3;
        x0.u = xu.x; x1.u = xu.y; x2.u = xu.z; x3.u = xu.w;
        H2 t0, t1, t2, t3, u0, u1, u2, u3;
        t0.h = x0.h + xr0.h; u0.u = t0.u & 0x7fff7fffu;
        t1.h = x1.h + xr1.h; u1.u = t1.u & 0x7fff7fffu;
        t2.h = x2.h + xr2.h; u2.u = t2.u & 0x7fff7fffu;
        t3.h = x3.h + xr3.h; u3.u = t3.u & 0x7fff7fffu;
        float p06 = __builtin_amdgcn_fdot2(t0.h, a06[0], 0.f, false);
        float p04 = __builtin_amdgcn_fdot2(u0.h, a04[0], 0.f, false);
        p06 = __builtin_amdgcn_fdot2(t1.h, a06[1], p06, false);
        p04 = __builtin_amdgcn_fdot2(u1.h, a04[1], p04, false);
        p06 = __builtin_amdgcn_fdot2(t2.h, a06[2], p06, false);
        p04 = __builtin_amdgcn_fdot2(u2.h, a04[2], p04, false);
        p06 = __builtin_amdgcn_fdot2(t3.h, a06[3], p06, false);
        p04 = __builtin_amdgcn_fdot2(u3.h, a04[3], p04, false);
        float p = grp8_sum(p06 + p04);
        const float w = valid ? __expf(fminf(p, 60.f)) : 0.f;
        const _Float16 wh = (_Float16)w;
        const half2v w2 = {wh, wh};
        acc0.h += w2 * x0.h;
        acc1.h += w2 * x1.h;
        acc2.h += w2 * x2.h;
        acc3.h += w2 * x3.h;
        den += w;
        xu = xun;
    }
    float af[8];
    af[0] = (float)acc0.h[0]; af[1] = (float)acc0.h[1];
    af[2] = (float)acc1.h[0]; af[3] = (float)acc1.h[1];
    af[4] = (float)acc2.h[0]; af[5] = (float)acc2.h[1];
    af[6] = (float)acc3.h[0]; af[7] = (float)acc3.h[1];
    #pragma unroll
    for (int d = 8; d < 64; d <<= 1) {
        #pragma unroll
        for (int k = 0; k < 8; ++k) af[k] += __shfl_xor(af[k], d);
        den += __shfl_xor(den, d);
    }
    if (lane < 8) {
        const float inv = 1.f / den;
        const uint4 biu = ((const uint4*)bias2)[lane];
        const uint4 gu  = ((const uint4*)g2)[lane];
        const uint4 bu  = ((const uint4*)bb2)[lane];
        const uint4 mu  = ((const uint4*)m2)[lane];
        const uint4 vu  = ((const uint4*)v2)[lane];
        const uint4 sku = ((const uint4*)xskip)[(size_t)n * 8 + lane];
        const uint4 wou = ((const uint4*)Wo)[lane];
        const uint bi_[8] = {biu.x, biu.x, biu.y, biu.y, biu.z, biu.z, biu.w, biu.w};
        const uint g_[8]  = {gu.x, gu.x, gu.y, gu.y, gu.z, gu.z, gu.w, gu.w};
        const uint b_[8]  = {bu.x, bu.x, bu.y, bu.y, bu.z, bu.z, bu.w, bu.w};
        const uint m_[8]  = {mu.x, mu.x, mu.y, mu.y, mu.z, mu.z, mu.w, mu.w};
        const uint v_[8]  = {vu.x, vu.x, vu.y, vu.y, vu.z, vu.z, vu.w, vu.w};
        const uint sk_[8] = {sku.x, sku.x, sku.y, sku.y, sku.z, sku.z, sku.w, sku.w};
        const uint wo_[8] = {wou.x, wou.x, wou.y, wou.y, wou.z, wou.z, wou.w, wou.w};
        float d = 0.f;
        #pragma unroll
        for (int k = 0; k < 8; ++k) {
            float bb = (k & 1) ? hi16(bi_[k]) : lo16(bi_[k]);
            float gg = (k & 1) ? hi16(g_[k])  : lo16(g_[k]);
            float bnb = (k & 1) ? hi16(b_[k]) : lo16(b_[k]);
            float mm = (k & 1) ? hi16(m_[k])  : lo16(m_[k]);
            float vv = (k & 1) ? hi16(v_[k])  : lo16(v_[k]);
            float sk = (k & 1) ? hi16(sk_[k]) : lo16(sk_[k]);
            float wo = (k & 1) ? hi16(wo_[k]) : lo16(wo_[k]);
            float o = fmaf(af[k], inv, bb);
            float sc = gg * rsqrtf(vv + BN_EPS);
            float hv = fmaxf((o - mm) * sc + bnb, 0.f) + sk;
            d = fmaf(hv, wo, d);
        }
        d = grp8_sum(d);   // sum over the 8 lanes (0..7)
        if (lane == 0) {
            float r = d + b2f(bo[0]);
            if (flags[0]) ((float*)out)[n] = r;
            else          ((ushort*)out)[n] = f2b(r);
        }
    }
}

extern "C" void kernel_launch(void* const* d_in, const int* in_sizes, int n_in,
                              void* d_out, int out_size, void* d_ws, size_t ws_size,
                              hipStream_t stream) {
    char* ws = (char*)d_ws;
    size_t off = 0;
    auto alloc = [&](size_t bytes) -> void* {
        void* p = ws + off;
        off += (bytes + 255) & ~(size_t)255;
        return p;
    };
    int*    flags   = (int*)alloc(256);
    ushort* params  = (ushort*)alloc((size_t)127617 * 2);
    ushort* att1h   = (ushort*)alloc(256 * 2);
    ushort* att2h   = (ushort*)alloc(64 * 2);
    ushort* x_c     = (ushort*)alloc((size_t)N_NODES * IN_DIM * 2);
    int*    row_ptr = (int*)alloc((size_t)(N_NODES + 1) * 4);
    int*    rowcur  = (int*)alloc((size_t)N_NODES * 4);
    int*    deg     = (int*)alloc((size_t)N_NODES * 4);
    int*    colbuf  = (int*)alloc((size_t)EP_EDGES * 4);
    int*    bsum    = (int*)alloc(64 * 4);
    ushort* xl1     = (ushort*)alloc((size_t)N_NODES * C1 * 2);   // fp16
    ushort* xr1     = (ushort*)alloc((size_t)N_NODES * C1 * 2);   // fp16
    ushort* xskip   = (ushort*)alloc((size_t)N_NODES * HID * 2);  // bf16
    ushort* h1      = (ushort*)alloc((size_t)N_NODES * C1 * 2);   // bf16
    ushort* xl2     = (ushort*)alloc((size_t)N_NODES * HID * 2);  // fp16
    ushort* xr2     = (ushort*)alloc((size_t)N_NODES * HID * 2);  // fp16
    ushort* swzWl1  = (ushort*)alloc((size_t)IN_DIM * C1 * 2);
    ushort* swzWr1  = (ushort*)alloc((size_t)IN_DIM * C1 * 2);
    ushort* swzWs   = (ushort*)alloc((size_t)IN_DIM * HID * 2);
    ushort* swzWl2  = (ushort*)alloc((size_t)C1 * HID * 2);
    ushort* swzWr2  = (ushort*)alloc((size_t)C1 * HID * 2);

    ushort* Wl1c   = params + 0;
    ushort* bl1c   = params + 40960;
    ushort* Wr1c   = params + 41216;
    ushort* br1c   = params + 82176;
    ushort* att1c  = params + 82432;
    ushort* bias1c = params + 82688;
    ushort* g1c    = params + 82944;
    ushort* b1c    = params + 83200;
    ushort* m1c    = params + 83456;
    ushort* v1c    = params + 83712;
    ushort* Wl2c   = params + 83968;
    ushort* bl2c   = params + 100352;
    ushort* Wr2c   = params + 100416;
    ushort* br2c   = params + 116800;
    ushort* att2c  = params + 116864;
    ushort* bias2c = params + 116928;
    ushort* g2c    = params + 116992;
    ushort* b2c    = params + 117056;
    ushort* m2c    = params + 117120;
    ushort* v2c    = params + 117184;
    ushort* Wsc    = params + 117248;
    ushort* bsc    = params + 127488;
    ushort* Woc    = params + 127552;
    ushort* boc    = params + 127616;

    // ---- detect dtypes & canonicalize ----
    detect_k<<<1, 64, 0, stream>>>((const ushort*)d_in[0], (const int*)d_in[1], flags);
    cvt_x_k<<<(N_NODES * IN_DIM + 255) / 256, 256, 0, stream>>>(d_in[0], x_c, flags, deg);
    PP pp;
    for (int i = 0; i < 24; ++i) pp.p[i] = d_in[2 + i];
    cvt_params_k<<<24, 256, 0, stream>>>(pp, params, flags);
    cvt_att_k<<<1, 320, 0, stream>>>(att1c, att2c, att1h, att2h);

    // ---- fused weight swizzles for MFMA ----
    SWZ sw;
    sw.W[0] = Wl1c;  sw.D[0] = swzWl1; sw.NT[0] = 16; sw.base[0] = 0;
    sw.W[1] = Wr1c;  sw.D[1] = swzWr1; sw.NT[1] = 16; sw.base[1] = 5120;
    sw.W[2] = Wsc;   sw.D[2] = swzWs;  sw.NT[2] = 4;  sw.base[2] = 10240;
    sw.W[3] = Wl2c;  sw.D[3] = swzWl2; sw.NT[3] = 4;  sw.base[3] = 11520;
    sw.W[4] = Wr2c;  sw.D[4] = swzWr2; sw.NT[4] = 4;  sw.base[4] = 13568;
    sw.total = 15616;
    swz_all_k<<<(15616 + 255) / 256, 256, 0, stream>>>(sw);

    const int NB_N = (N_NODES + 255) / 256;        // 196
    const int NB_E = (EP_EDGES + 255) / 256;       // 3321
    const int NB_S = (N_NODES + 1023) / 1024;      // 49

    // ---- CSR build (reads raw edge_index) ----
    const int* ei_raw = (const int*)d_in[1];
    hist_k<<<NB_E, 256, 0, stream>>>(ei_raw, flags, deg);
    scan1_k<<<NB_S, 1024, 0, stream>>>(deg, row_ptr, bsum);
    scan2_k<<<1, 64, 0, stream>>>(bsum, NB_S);
    scan3_k<<<NB_N, 256, 0, stream>>>(row_ptr, bsum, rowcur);
    scatter_k<<<NB_E, 256, 0, stream>>>(ei_raw, flags, rowcur, colbuf);

    // ---- layer-1 linear transforms (+ skip), fused MFMA ----
    const int GB = (N_NODES + 63) / 64;  // 782 blocks of 4 waves x 16 rows
    gemm3_k<<<GB, 256, 0, stream>>>(x_c, swzWl1, swzWr1, swzWs, bl1c, br1c, bsc,
                                    xl1, xr1, xskip, N_NODES);

    // ---- conv1 edge aggregation + BN1 + relu ----
    conv1_k<<<N_NODES, 256, 0, stream>>>(xl1, xr1, row_ptr, colbuf, att1h, bias1c,
                                         g1c, b1c, m1c, v1c, h1);

    // ---- layer-2 linear transforms, fused MFMA ----
    gemm2_k<<<GB, 256, 0, stream>>>(h1, swzWl2, swzWr2, bl2c, br2c, xl2, xr2, N_NODES);

    // ---- conv2 + BN2 + relu + skip + output linear ----
    conv2_k<<<(N_NODES + 3) / 4, 256, 0, stream>>>(xl2, xr2, xskip, row_ptr, colbuf,
                                                   att2h, bias2c, g2c, b2c, m2c, v2c,
                                                   Woc, boc, d_out, flags);
}

// Round 7
// 436.189 us; speedup vs baseline: 1.2226x; 1.2226x over previous
//
#include <hip/hip_runtime.h>
#include <hip/hip_bf16.h>

#define N_NODES 50000
#define E_EDGES 800000
#define EP_EDGES 850000   // E + N self loops
#define IN_DIM 160
#define HEADS 4
#define HID 64
#define C1 256            // HEADS*HID
#define NEG_SLOPE 0.2f
#define BN_EPS 1e-5f

typedef __attribute__((ext_vector_type(8))) short bf16x8;
typedef __attribute__((ext_vector_type(4))) float f32x4;

__device__ __forceinline__ float b2f(ushort u) {
    return __uint_as_float(((unsigned)u) << 16);
}
__device__ __forceinline__ ushort f2b(float f) {
    __hip_bfloat16 h = __float2bfloat16(f);
    return *reinterpret_cast<ushort*>(&h);
}
__device__ __forceinline__ float lo16(uint u) { return __uint_as_float(u << 16); }
__device__ __forceinline__ float hi16(uint u) { return __uint_as_float(u & 0xffff0000u); }

// DPP-based add of a permuted copy: pure VALU pipe
template<int CTRL>
__device__ __forceinline__ float dpp_add(float p) {
    int t = __builtin_amdgcn_update_dpp(0, __float_as_int(p), CTRL, 0xf, 0xf, true);
    return p + __int_as_float(t);
}
// sum over each 16-lane row; all 16 lanes get the row total
__device__ __forceinline__ float row16_sum(float p) {
    p = dpp_add<0xB1>(p);    // quad_perm xor1
    p = dpp_add<0x4E>(p);    // quad_perm xor2
    p = dpp_add<0x124>(p);   // row_ror:4
    p = dpp_add<0x128>(p);   // row_ror:8
    return p;
}

// ---------------- runtime dtype detection ----------------
// flags[0]: 1 if float tensors are fp32 on device; flags[1]: 1 if edges int64
__global__ void detect_k(const ushort* __restrict__ xraw,
                         const int* __restrict__ eraw,
                         int* __restrict__ flags) {
    int lane = threadIdx.x;  // 64 threads
    int good = 0, nz = 0;
    for (int i = lane; i < 256; i += 64) {
        float a = fabsf(b2f(xraw[2 * i]));
        good += (a > 1e-6f && a < 1e6f) ? 1 : 0;
        nz += (eraw[2 * i + 1] != 0) ? 1 : 0;
    }
    #pragma unroll
    for (int off = 32; off > 0; off >>= 1) {
        good += __shfl_xor(good, off);
        nz += __shfl_xor(nz, off);
    }
    if (lane == 0) {
        flags[0] = (good < 192) ? 1 : 0;
        flags[1] = (nz == 0) ? 1 : 0;
    }
}

// ---------------- canonicalize x -> bf16 (also zeroes deg) ----------------
__global__ void cvt_x_k(const void* __restrict__ src, ushort* __restrict__ dst,
                        const int* __restrict__ flags, int* __restrict__ deg) {
    int i = blockIdx.x * 256 + threadIdx.x;
    if (i < N_NODES) deg[i] = 0;
    if (i >= N_NODES * IN_DIM) return;
    dst[i] = flags[0] ? f2b(((const float*)src)[i]) : ((const ushort*)src)[i];
}

// ---------------- merged: weight swizzle (raw->MFMA frag order) + small-param canonicalize ----------------
struct SW2 {
    const void* W[5];    // raw Wl1, Wr1, Ws, Wl2, Wr2
    ushort* D[5];
    int NT[5];
    int base[5];
    const void* sp[19];  // raw small tensors
};

__global__ void swzp_k(SW2 s, ushort* __restrict__ params,
                       const int* __restrict__ flags) {
    const bool f32 = flags[0] != 0;
    if (blockIdx.x < 61) {
        int idx = blockIdx.x * 256 + threadIdx.x;   // < 15616
        int seg = 0;
        #pragma unroll
        for (int k = 1; k < 5; ++k) seg += (idx >= s.base[k]) ? 1 : 0;
        int li = idx - s.base[seg];
        int NT = s.NT[seg];
        int N = NT << 4;
        int lane = li & 63;
        int ft = li >> 6;
        int kb = ft / NT, t = ft - kb * NT;
        int q = lane >> 4, m = lane & 15;
        const float* pf = (const float*)s.W[seg];
        const ushort* pu = (const ushort*)s.W[seg];
        ushort* d = s.D[seg] + (size_t)li * 8;
        #pragma unroll
        for (int j = 0; j < 8; ++j) {
            size_t src = (size_t)(kb * 32 + q * 8 + j) * N + t * 16 + m;
            d[j] = f32 ? f2b(pf[src]) : pu[src];
        }
    } else {
        const int SZ[19] = {256,256,256,256,256,256,256,256,
                            64,64,64,64,64,64,64,64,64,64, 1};
        const int OF[19] = {40960,82176,82432,82688,82944,83200,83456,83712,
                            100352,116800,116864,116928,116992,117056,117120,117184,
                            127488,127552, 127616};
        for (int e = threadIdx.x; e < 2689; e += 256) {
            int rem = e, t = 0;
            while (rem >= SZ[t]) { rem -= SZ[t]; ++t; }
            const float* pf = (const float*)s.sp[t];
            const ushort* pu = (const ushort*)s.sp[t];
            params[OF[t] + rem] = f32 ? f2b(pf[rem]) : pu[rem];
        }
    }
}

// ---------------- CSR build (reads raw edge_index, flag-dependent stride) ----------------
__global__ void hist_k(const int* __restrict__ ei, const int* __restrict__ flags,
                       int* __restrict__ deg) {
    int e = blockIdx.x * 256 + threadIdx.x;
    if (e >= EP_EDGES) return;
    int dst;
    if (e < E_EDGES) {
        int idx = E_EDGES + e;
        dst = flags[1] ? ei[2 * idx] : ei[idx];
    } else dst = e - E_EDGES;
    atomicAdd(&deg[dst], 1);
}

__global__ __launch_bounds__(1024) void scan1_k(const int* __restrict__ deg,
                                                int* __restrict__ exc,
                                                int* __restrict__ bsum) {
    __shared__ int s[1024];
    int i = blockIdx.x * 1024 + threadIdx.x;
    int v = (i < N_NODES) ? deg[i] : 0;
    s[threadIdx.x] = v;
    __syncthreads();
    for (int off = 1; off < 1024; off <<= 1) {
        int t = (threadIdx.x >= off) ? s[threadIdx.x - off] : 0;
        __syncthreads();
        s[threadIdx.x] += t;
        __syncthreads();
    }
    if (i < N_NODES) exc[i] = s[threadIdx.x] - v;
    if (threadIdx.x == 1023) bsum[blockIdx.x] = s[1023];
}

__global__ void scan2_k(int* __restrict__ bsum, int nb) {
    int lane = threadIdx.x;  // single wave of 64
    int v = (lane < nb) ? bsum[lane] : 0;
    int orig = v;
    #pragma unroll
    for (int d = 1; d < 64; d <<= 1) {
        int t = __shfl_up(v, d);
        if (lane >= d) v += t;
    }
    if (lane < nb) bsum[lane] = v - orig;
}

__global__ void scan3_k(int* __restrict__ row_ptr, const int* __restrict__ bsum,
                        int* __restrict__ rowcur) {
    int i = blockIdx.x * 256 + threadIdx.x;
    if (i >= N_NODES) return;
    int rp = row_ptr[i] + bsum[i >> 10];
    row_ptr[i] = rp;
    rowcur[i] = rp;
    if (i == 0) row_ptr[N_NODES] = EP_EDGES;
}

__global__ void scatter_k(const int* __restrict__ ei, const int* __restrict__ flags,
                          int* __restrict__ rowcur, int* __restrict__ col) {
    int e = blockIdx.x * 256 + threadIdx.x;
    if (e >= EP_EDGES) return;
    int src, dst;
    if (e < E_EDGES) {
        if (flags[1]) { src = ei[2 * e]; dst = ei[2 * (E_EDGES + e)]; }
        else          { src = ei[e];     dst = ei[E_EDGES + e]; }
    } else { src = e - E_EDGES; dst = src; }
    int pos = atomicAdd(&rowcur[dst], 1);
    col[pos] = src;
}

// ---------------- fused layer-1 MFMA GEMM, split-N, 2 row-tiles/wave ----------------
// Grid (ceil(M/128), 2): blockIdx.y = column half. Wave = 32 rows.
// Each B-fragment load feeds 2 MFMAs (row-tiles) -> half the L2 B-traffic of v1.
__global__ __launch_bounds__(256) void gemm3_k(const ushort* __restrict__ A,
                                               const ushort* __restrict__ B1,
                                               const ushort* __restrict__ B2,
                                               const ushort* __restrict__ B3,
                                               const ushort* __restrict__ bi1,
                                               const ushort* __restrict__ bi2,
                                               const ushort* __restrict__ bi3,
                                               ushort* __restrict__ o1,
                                               ushort* __restrict__ o2,
                                               ushort* __restrict__ o3,
                                               int M) {
    const int wave = threadIdx.x >> 6;
    const int lane = threadIdx.x & 63;
    const int ch = blockIdx.y;               // col-half: B1/B2 tiles [ch*8,ch*8+8), B3 tiles [ch*2,ch*2+2)
    const int row0 = blockIdx.x * 128 + wave * 32;
    if (row0 >= M) return;
    int ar0 = row0 + (lane & 15);      if (ar0 >= M) ar0 = M - 1;
    int ar1 = row0 + 16 + (lane & 15); if (ar1 >= M) ar1 = M - 1;
    const ushort* ap0 = A + (size_t)ar0 * IN_DIM + (lane >> 4) * 8;
    const ushort* ap1 = A + (size_t)ar1 * IN_DIM + (lane >> 4) * 8;
    bf16x8 af0[5], af1[5];
    #pragma unroll
    for (int kb = 0; kb < 5; ++kb) {
        af0[kb] = *(const bf16x8*)(ap0 + kb * 32);
        af1[kb] = *(const bf16x8*)(ap1 + kb * 32);
    }
    const bf16x8* b1 = (const bf16x8*)B1;
    const bf16x8* b2 = (const bf16x8*)B2;
    const bf16x8* b3 = (const bf16x8*)B3;
    f32x4 aL[2][8] = {}, aR[2][8] = {}, aS[2][2] = {};
    #pragma unroll
    for (int kb = 0; kb < 5; ++kb) {
        #pragma unroll
        for (int j = 0; j < 8; ++j) {
            bf16x8 b = b1[(kb * 16 + ch * 8 + j) * 64 + lane];
            aL[0][j] = __builtin_amdgcn_mfma_f32_16x16x32_bf16(af0[kb], b, aL[0][j], 0, 0, 0);
            aL[1][j] = __builtin_amdgcn_mfma_f32_16x16x32_bf16(af1[kb], b, aL[1][j], 0, 0, 0);
        }
        #pragma unroll
        for (int j = 0; j < 8; ++j) {
            bf16x8 b = b2[(kb * 16 + ch * 8 + j) * 64 + lane];
            aR[0][j] = __builtin_amdgcn_mfma_f32_16x16x32_bf16(af0[kb], b, aR[0][j], 0, 0, 0);
            aR[1][j] = __builtin_amdgcn_mfma_f32_16x16x32_bf16(af1[kb], b, aR[1][j], 0, 0, 0);
        }
        #pragma unroll
        for (int j = 0; j < 2; ++j) {
            bf16x8 b = b3[(kb * 4 + ch * 2 + j) * 64 + lane];
            aS[0][j] = __builtin_amdgcn_mfma_f32_16x16x32_bf16(af0[kb], b, aS[0][j], 0, 0, 0);
            aS[1][j] = __builtin_amdgcn_mfma_f32_16x16x32_bf16(af1[kb], b, aS[1][j], 0, 0, 0);
        }
    }
    const int cn = lane & 15, cq = lane >> 4;
    #pragma unroll
    for (int rt = 0; rt < 2; ++rt) {
        #pragma unroll
        for (int j = 0; j < 8; ++j) {
            int colc = (ch * 8 + j) * 16 + cn;
            float bbL = b2f(bi1[colc]);
            float bbR = b2f(bi2[colc]);
            #pragma unroll
            for (int r = 0; r < 4; ++r) {
                int grow = row0 + rt * 16 + cq * 4 + r;
                if (grow < M) {
                    o1[(size_t)grow * C1 + colc] = f2b(aL[rt][j][r] + bbL);
                    o2[(size_t)grow * C1 + colc] = f2b(aR[rt][j][r] + bbR);
                }
            }
        }
        #pragma unroll
        for (int j = 0; j < 2; ++j) {
            int colc = (ch * 2 + j) * 16 + cn;
            float bb = b2f(bi3[colc]);
            #pragma unroll
            for (int r = 0; r < 4; ++r) {
                int grow = row0 + rt * 16 + cq * 4 + r;
                if (grow < M)
                    o3[(size_t)grow * HID + colc] = f2b(aS[rt][j][r] + bb);
            }
        }
    }
}

// ---------------- fused layer-2 MFMA GEMM: xl2(64) + xr2(64), K=256 ----------------
__global__ __launch_bounds__(256) void gemm2_k(const ushort* __restrict__ A,
                                               const ushort* __restrict__ B1,
                                               const ushort* __restrict__ B2,
                                               const ushort* __restrict__ bi1,
                                               const ushort* __restrict__ bi2,
                                               ushort* __restrict__ o1,
                                               ushort* __restrict__ o2,
                                               int M) {
    const int wave = threadIdx.x >> 6;
    const int lane = threadIdx.x & 63;
    const int row0 = blockIdx.x * 64 + wave * 16;
    if (row0 >= M) return;
    int arow = row0 + (lane & 15);
    if (arow >= M) arow = M - 1;
    const ushort* aptr = A + (size_t)arow * C1 + (lane >> 4) * 8;
    const bf16x8* b1 = (const bf16x8*)B1;
    const bf16x8* b2 = (const bf16x8*)B2;
    f32x4 aL[4] = {}, aR[4] = {};
    #pragma unroll
    for (int kb = 0; kb < 8; ++kb) {
        bf16x8 af = *(const bf16x8*)(aptr + kb * 32);
        #pragma unroll
        for (int t = 0; t < 4; ++t)
            aL[t] = __builtin_amdgcn_mfma_f32_16x16x32_bf16(af, b1[(kb * 4 + t) * 64 + lane], aL[t], 0, 0, 0);
        #pragma unroll
        for (int t = 0; t < 4; ++t)
            aR[t] = __builtin_amdgcn_mfma_f32_16x16x32_bf16(af, b2[(kb * 4 + t) * 64 + lane], aR[t], 0, 0, 0);
    }
    const int cn = lane & 15, cq = lane >> 4;
    #pragma unroll
    for (int t = 0; t < 4; ++t) {
        float bbL = b2f(bi1[t * 16 + cn]);
        float bbR = b2f(bi2[t * 16 + cn]);
        #pragma unroll
        for (int r = 0; r < 4; ++r) {
            int grow = row0 + cq * 4 + r;
            if (grow < M) {
                o1[(size_t)grow * HID + t * 16 + cn] = f2b(aL[t][r] + bbL);
                o2[(size_t)grow * HID + t * 16 + cn] = f2b(aR[t][r] + bbR);
            }
        }
    }
}

// ---------------- conv1: 8 edges/trip, 16 lanes/edge, 4 ch/lane, DPP reduce ----------------
__global__ __launch_bounds__(256) void conv1_k(const ushort* __restrict__ xl,
                                               const ushort* __restrict__ xr,
                                               const int* __restrict__ row_ptr,
                                               const int* __restrict__ col,
                                               const ushort* __restrict__ att,
                                               const ushort* __restrict__ bias1,
                                               const ushort* __restrict__ g1,
                                               const ushort* __restrict__ b1,
                                               const ushort* __restrict__ m1,
                                               const ushort* __restrict__ v1,
                                               ushort* __restrict__ h1out) {
    const int n = blockIdx.x;
    const int h = threadIdx.x >> 6;          // wave = head
    const int lane = threadIdx.x & 63;
    const int grp = lane >> 4;               // edge slot 0..3
    const int m = lane & 15;                 // channel quad
    const uint cpi = h * 16 + m;             // uint2 index within 64-uint2 row
    const uint2* xl2v = (const uint2*)xl;
    const uint2 xru = ((const uint2*)xr)[(size_t)n * 64 + cpi];
    const float xr0 = lo16(xru.x), xr1 = hi16(xru.x);
    const float xr2 = lo16(xru.y), xr3 = hi16(xru.y);
    const uint2 atu = ((const uint2*)att)[cpi];
    const float at0 = lo16(atu.x), at1 = hi16(atu.x);
    const float at2 = lo16(atu.y), at3 = hi16(atu.y);
    const int e0 = row_ptr[n], e1 = row_ptr[n + 1];
    float a0 = 0.f, a1 = 0.f, a2 = 0.f, a3 = 0.f, den = 0.f;
    const int jA = e0 + grp, jB = e0 + 4 + grp;
    uint sA = (uint)col[jA < e1 ? jA : e1 - 1];
    uint sB = (uint)col[jB < e1 ? jB : e1 - 1];
    for (int i = e0; i < e1; i += 8) {
        const uint2 xuA = xl2v[(sA << 6) + cpi];   // 32-bit index
        const uint2 xuB = xl2v[(sB << 6) + cpi];
        const int jC = i + 8 + grp, jD = i + 12 + grp;
        const uint sC = (uint)col[jC < e1 ? jC : e1 - 1];
        const uint sD = (uint)col[jD < e1 ? jD : e1 - 1];
        const bool vA = (i + grp) < e1, vB = (i + 4 + grp) < e1;
        // edge A
        const float xa0 = lo16(xuA.x), xa1 = hi16(xuA.x);
        const float xa2 = lo16(xuA.y), xa3 = hi16(xuA.y);
        float ta0 = xa0 + xr0; ta0 = fmaxf(ta0, ta0 * NEG_SLOPE);
        float ta1 = xa1 + xr1; ta1 = fmaxf(ta1, ta1 * NEG_SLOPE);
        float ta2 = xa2 + xr2; ta2 = fmaxf(ta2, ta2 * NEG_SLOPE);
        float ta3 = xa3 + xr3; ta3 = fmaxf(ta3, ta3 * NEG_SLOPE);
        float pA = fmaf(ta0, at0, fmaf(ta1, at1, fmaf(ta2, at2, ta3 * at3)));
        pA = row16_sum(pA);
        const float wA = vA ? __expf(fminf(pA, 60.f)) : 0.f;
        // edge B
        const float xb0 = lo16(xuB.x), xb1 = hi16(xuB.x);
        const float xb2 = lo16(xuB.y), xb3 = hi16(xuB.y);
        float tb0 = xb0 + xr0; tb0 = fmaxf(tb0, tb0 * NEG_SLOPE);
        float tb1 = xb1 + xr1; tb1 = fmaxf(tb1, tb1 * NEG_SLOPE);
        float tb2 = xb2 + xr2; tb2 = fmaxf(tb2, tb2 * NEG_SLOPE);
        float tb3 = xb3 + xr3; tb3 = fmaxf(tb3, tb3 * NEG_SLOPE);
        float pB = fmaf(tb0, at0, fmaf(tb1, at1, fmaf(tb2, at2, tb3 * at3)));
        pB = row16_sum(pB);
        const float wB = vB ? __expf(fminf(pB, 60.f)) : 0.f;
        // accumulate
        a0 = fmaf(wA, xa0, a0); a0 = fmaf(wB, xb0, a0);
        a1 = fmaf(wA, xa1, a1); a1 = fmaf(wB, xb1, a1);
        a2 = fmaf(wA, xa2, a2); a2 = fmaf(wB, xb2, a2);
        a3 = fmaf(wA, xa3, a3); a3 = fmaf(wB, xb3, a3);
        den += wA + wB;
        sA = sC; sB = sD;
    }
    a0 += __shfl_xor(a0, 16); a0 += __shfl_xor(a0, 32);
    a1 += __shfl_xor(a1, 16); a1 += __shfl_xor(a1, 32);
    a2 += __shfl_xor(a2, 16); a2 += __shfl_xor(a2, 32);
    a3 += __shfl_xor(a3, 16); a3 += __shfl_xor(a3, 32);
    den += __shfl_xor(den, 16); den += __shfl_xor(den, 32);
    if (lane < 16) {
        const float inv = 1.f / den;
        const uint2 biu = ((const uint2*)bias1)[cpi];
        const uint2 gu  = ((const uint2*)g1)[cpi];
        const uint2 bu  = ((const uint2*)b1)[cpi];
        const uint2 mu  = ((const uint2*)m1)[cpi];
        const uint2 vu  = ((const uint2*)v1)[cpi];
        float o0 = fmaf(a0, inv, lo16(biu.x));
        float o1 = fmaf(a1, inv, hi16(biu.x));
        float o2 = fmaf(a2, inv, lo16(biu.y));
        float o3 = fmaf(a3, inv, hi16(biu.y));
        float s0 = lo16(gu.x) * rsqrtf(lo16(vu.x) + BN_EPS);
        float s1 = hi16(gu.x) * rsqrtf(hi16(vu.x) + BN_EPS);
        float s2 = lo16(gu.y) * rsqrtf(lo16(vu.y) + BN_EPS);
        float s3 = hi16(gu.y) * rsqrtf(hi16(vu.y) + BN_EPS);
        float h0 = fmaxf((o0 - lo16(mu.x)) * s0 + lo16(bu.x), 0.f);
        float h1v = fmaxf((o1 - hi16(mu.x)) * s1 + hi16(bu.x), 0.f);
        float h2 = fmaxf((o2 - lo16(mu.y)) * s2 + lo16(bu.y), 0.f);
        float h3 = fmaxf((o3 - hi16(mu.y)) * s3 + hi16(bu.y), 0.f);
        uint2 ou;
        ou.x = (uint)f2b(h0) | ((uint)f2b(h1v) << 16);
        ou.y = (uint)f2b(h2) | ((uint)f2b(h3) << 16);
        ((uint2*)h1out)[(size_t)n * 64 + cpi] = ou;
    }
}

// ---------------- conv2 + BN2 + relu + skip + output linear ----------------
__global__ __launch_bounds__(256) void conv2_k(const ushort* __restrict__ xl,
                                               const ushort* __restrict__ xr,
                                               const ushort* __restrict__ xskip,
                                               const int* __restrict__ row_ptr,
                                               const int* __restrict__ col,
                                               const ushort* __restrict__ att2,
                                               const ushort* __restrict__ bias2,
                                               const ushort* __restrict__ g2,
                                               const ushort* __restrict__ bb2,
                                               const ushort* __restrict__ m2,
                                               const ushort* __restrict__ v2,
                                               const ushort* __restrict__ Wo,
                                               const ushort* __restrict__ bo,
                                               void* __restrict__ out,
                                               const int* __restrict__ flags) {
    const int n = blockIdx.x * 4 + (threadIdx.x >> 6);
    if (n >= N_NODES) return;
    const int lane = threadIdx.x & 63;
    const int grp = lane >> 4;
    const uint m = lane & 15;                // uint2 index within 16-uint2 row
    const uint2* xl2v = (const uint2*)xl;
    const uint2 xru = ((const uint2*)xr)[(size_t)n * 16 + m];
    const float xr0 = lo16(xru.x), xr1 = hi16(xru.x);
    const float xr2 = lo16(xru.y), xr3 = hi16(xru.y);
    const uint2 atu = ((const uint2*)att2)[m];
    const float at0 = lo16(atu.x), at1 = hi16(atu.x);
    const float at2 = lo16(atu.y), at3 = hi16(atu.y);
    const int e0 = row_ptr[n], e1 = row_ptr[n + 1];
    float a0 = 0.f, a1 = 0.f, a2 = 0.f, a3 = 0.f, den = 0.f;
    const int jA = e0 + grp, jB = e0 + 4 + grp;
    uint sA = (uint)col[jA < e1 ? jA : e1 - 1];
    uint sB = (uint)col[jB < e1 ? jB : e1 - 1];
    for (int i = e0; i < e1; i += 8) {
        const uint2 xuA = xl2v[(sA << 4) + m];
        const uint2 xuB = xl2v[(sB << 4) + m];
        const int jC = i + 8 + grp, jD = i + 12 + grp;
        const uint sC = (uint)col[jC < e1 ? jC : e1 - 1];
        const uint sD = (uint)col[jD < e1 ? jD : e1 - 1];
        const bool vA = (i + grp) < e1, vB = (i + 4 + grp) < e1;
        const float xa0 = lo16(xuA.x), xa1 = hi16(xuA.x);
        const float xa2 = lo16(xuA.y), xa3 = hi16(xuA.y);
        float ta0 = xa0 + xr0; ta0 = fmaxf(ta0, ta0 * NEG_SLOPE);
        float ta1 = xa1 + xr1; ta1 = fmaxf(ta1, ta1 * NEG_SLOPE);
        float ta2 = xa2 + xr2; ta2 = fmaxf(ta2, ta2 * NEG_SLOPE);
        float ta3 = xa3 + xr3; ta3 = fmaxf(ta3, ta3 * NEG_SLOPE);
        float pA = fmaf(ta0, at0, fmaf(ta1, at1, fmaf(ta2, at2, ta3 * at3)));
        pA = row16_sum(pA);
        const float wA = vA ? __expf(fminf(pA, 60.f)) : 0.f;
        const float xb0 = lo16(xuB.x), xb1 = hi16(xuB.x);
        const float xb2 = lo16(xuB.y), xb3 = hi16(xuB.y);
        float tb0 = xb0 + xr0; tb0 = fmaxf(tb0, tb0 * NEG_SLOPE);
        float tb1 = xb1 + xr1; tb1 = fmaxf(tb1, tb1 * NEG_SLOPE);
        float tb2 = xb2 + xr2; tb2 = fmaxf(tb2, tb2 * NEG_SLOPE);
        float tb3 = xb3 + xr3; tb3 = fmaxf(tb3, tb3 * NEG_SLOPE);
        float pB = fmaf(tb0, at0, fmaf(tb1, at1, fmaf(tb2, at2, tb3 * at3)));
        pB = row16_sum(pB);
        const float wB = vB ? __expf(fminf(pB, 60.f)) : 0.f;
        a0 = fmaf(wA, xa0, a0); a0 = fmaf(wB, xb0, a0);
        a1 = fmaf(wA, xa1, a1); a1 = fmaf(wB, xb1, a1);
        a2 = fmaf(wA, xa2, a2); a2 = fmaf(wB, xb2, a2);
        a3 = fmaf(wA, xa3, a3); a3 = fmaf(wB, xb3, a3);
        den += wA + wB;
        sA = sC; sB = sD;
    }
    a0 += __shfl_xor(a0, 16); a0 += __shfl_xor(a0, 32);
    a1 += __shfl_xor(a1, 16); a1 += __shfl_xor(a1, 32);
    a2 += __shfl_xor(a2, 16); a2 += __shfl_xor(a2, 32);
    a3 += __shfl_xor(a3, 16); a3 += __shfl_xor(a3, 32);
    den += __shfl_xor(den, 16); den += __shfl_xor(den, 32);
    if (lane < 16) {
        const float inv = 1.f / den;
        const uint2 biu = ((const uint2*)bias2)[m];
        const uint2 gu  = ((const uint2*)g2)[m];
        const uint2 bu  = ((const uint2*)bb2)[m];
        const uint2 mu  = ((const uint2*)m2)[m];
        const uint2 vu  = ((const uint2*)v2)[m];
        const uint2 sku = ((const uint2*)xskip)[(size_t)n * 16 + m];
        const uint2 wou = ((const uint2*)Wo)[m];
        float o0 = fmaf(a0, inv, lo16(biu.x));
        float o1 = fmaf(a1, inv, hi16(biu.x));
        float o2 = fmaf(a2, inv, lo16(biu.y));
        float o3 = fmaf(a3, inv, hi16(biu.y));
        float s0 = lo16(gu.x) * rsqrtf(lo16(vu.x) + BN_EPS);
        float s1 = hi16(gu.x) * rsqrtf(hi16(vu.x) + BN_EPS);
        float s2 = lo16(gu.y) * rsqrtf(lo16(vu.y) + BN_EPS);
        float s3 = hi16(gu.y) * rsqrtf(hi16(vu.y) + BN_EPS);
        float h0 = fmaxf((o0 - lo16(mu.x)) * s0 + lo16(bu.x), 0.f) + lo16(sku.x);
        float h1v = fmaxf((o1 - hi16(mu.x)) * s1 + hi16(bu.x), 0.f) + hi16(sku.x);
        float h2 = fmaxf((o2 - lo16(mu.y)) * s2 + lo16(bu.y), 0.f) + lo16(sku.y);
        float h3 = fmaxf((o3 - hi16(mu.y)) * s3 + hi16(bu.y), 0.f) + hi16(sku.y);
        float d = fmaf(h0, lo16(wou.x), fmaf(h1v, hi16(wou.x),
                  fmaf(h2, lo16(wou.y), h3 * hi16(wou.y))));
        d = row16_sum(d);
        if (m == 0) {
            float r = d + b2f(bo[0]);
            if (flags[0]) ((float*)out)[n] = r;
            else          ((ushort*)out)[n] = f2b(r);
        }
    }
}

extern "C" void kernel_launch(void* const* d_in, const int* in_sizes, int n_in,
                              void* d_out, int out_size, void* d_ws, size_t ws_size,
                              hipStream_t stream) {
    char* ws = (char*)d_ws;
    size_t off = 0;
    auto alloc = [&](size_t bytes) -> void* {
        void* p = ws + off;
        off += (bytes + 255) & ~(size_t)255;
        return p;
    };
    int*    flags   = (int*)alloc(256);
    ushort* params  = (ushort*)alloc((size_t)127617 * 2);
    ushort* x_c     = (ushort*)alloc((size_t)N_NODES * IN_DIM * 2);
    int*    row_ptr = (int*)alloc((size_t)(N_NODES + 1) * 4);
    int*    rowcur  = (int*)alloc((size_t)N_NODES * 4);
    int*    deg     = (int*)alloc((size_t)N_NODES * 4);
    int*    colbuf  = (int*)alloc((size_t)EP_EDGES * 4);
    int*    bsum    = (int*)alloc(64 * 4);
    ushort* xl1     = (ushort*)alloc((size_t)N_NODES * C1 * 2);
    ushort* xr1     = (ushort*)alloc((size_t)N_NODES * C1 * 2);
    ushort* xskip   = (ushort*)alloc((size_t)N_NODES * HID * 2);
    ushort* h1      = (ushort*)alloc((size_t)N_NODES * C1 * 2);
    ushort* xl2     = (ushort*)alloc((size_t)N_NODES * HID * 2);
    ushort* xr2     = (ushort*)alloc((size_t)N_NODES * HID * 2);
    ushort* swzWl1  = (ushort*)alloc((size_t)IN_DIM * C1 * 2);
    ushort* swzWr1  = (ushort*)alloc((size_t)IN_DIM * C1 * 2);
    ushort* swzWs   = (ushort*)alloc((size_t)IN_DIM * HID * 2);
    ushort* swzWl2  = (ushort*)alloc((size_t)C1 * HID * 2);
    ushort* swzWr2  = (ushort*)alloc((size_t)C1 * HID * 2);

    ushort* bl1c   = params + 40960;
    ushort* br1c   = params + 82176;
    ushort* att1c  = params + 82432;
    ushort* bias1c = params + 82688;
    ushort* g1c    = params + 82944;
    ushort* b1c    = params + 83200;
    ushort* m1c    = params + 83456;
    ushort* v1c    = params + 83712;
    ushort* bl2c   = params + 100352;
    ushort* br2c   = params + 116800;
    ushort* att2c  = params + 116864;
    ushort* bias2c = params + 116928;
    ushort* g2c    = params + 116992;
    ushort* b2c    = params + 117056;
    ushort* m2c    = params + 117120;
    ushort* v2c    = params + 117184;
    ushort* bsc    = params + 127488;
    ushort* Woc    = params + 127552;
    ushort* boc    = params + 127616;

    // ---- detect dtypes, canonicalize x, swizzle weights + small params ----
    detect_k<<<1, 64, 0, stream>>>((const ushort*)d_in[0], (const int*)d_in[1], flags);
    cvt_x_k<<<(N_NODES * IN_DIM + 255) / 256, 256, 0, stream>>>(d_in[0], x_c, flags, deg);

    SW2 sw;
    sw.W[0] = d_in[2];  sw.D[0] = swzWl1; sw.NT[0] = 16; sw.base[0] = 0;      // Wl1
    sw.W[1] = d_in[4];  sw.D[1] = swzWr1; sw.NT[1] = 16; sw.base[1] = 5120;   // Wr1
    sw.W[2] = d_in[22]; sw.D[2] = swzWs;  sw.NT[2] = 4;  sw.base[2] = 10240;  // Ws
    sw.W[3] = d_in[12]; sw.D[3] = swzWl2; sw.NT[3] = 4;  sw.base[3] = 11520;  // Wl2
    sw.W[4] = d_in[14]; sw.D[4] = swzWr2; sw.NT[4] = 4;  sw.base[4] = 13568;  // Wr2
    const int spidx[19] = {3,5,6,7,8,9,10,11, 13,15,16,17,18,19,20,21, 23,24, 25};
    for (int i = 0; i < 19; ++i) sw.sp[i] = d_in[spidx[i]];
    swzp_k<<<62, 256, 0, stream>>>(sw, params, flags);

    const int NB_N = (N_NODES + 255) / 256;        // 196
    const int NB_E = (EP_EDGES + 255) / 256;       // 3321
    const int NB_S = (N_NODES + 1023) / 1024;      // 49

    // ---- CSR build (reads raw edge_index) ----
    const int* ei_raw = (const int*)d_in[1];
    hist_k<<<NB_E, 256, 0, stream>>>(ei_raw, flags, deg);
    scan1_k<<<NB_S, 1024, 0, stream>>>(deg, row_ptr, bsum);
    scan2_k<<<1, 64, 0, stream>>>(bsum, NB_S);
    scan3_k<<<NB_N, 256, 0, stream>>>(row_ptr, bsum, rowcur);
    scatter_k<<<NB_E, 256, 0, stream>>>(ei_raw, flags, rowcur, colbuf);

    // ---- layer-1 linear transforms (+ skip), fused MFMA (split-N, 2 row-tiles/wave) ----
    gemm3_k<<<dim3((N_NODES + 127) / 128, 2), 256, 0, stream>>>(
        x_c, swzWl1, swzWr1, swzWs, bl1c, br1c, bsc, xl1, xr1, xskip, N_NODES);

    // ---- conv1 edge aggregation + BN1 + relu ----
    conv1_k<<<N_NODES, 256, 0, stream>>>(xl1, xr1, row_ptr, colbuf, att1c, bias1c,
                                         g1c, b1c, m1c, v1c, h1);

    // ---- layer-2 linear transforms, fused MFMA ----
    gemm2_k<<<(N_NODES + 63) / 64, 256, 0, stream>>>(h1, swzWl2, swzWr2, bl2c, br2c,
                                                     xl2, xr2, N_NODES);

    // ---- conv2 + BN2 + relu + skip + output linear ----
    conv2_k<<<(N_NODES + 3) / 4, 256, 0, stream>>>(xl2, xr2, xskip, row_ptr, colbuf,
                                                   att2c, bias2c, g2c, b2c, m2c, v2c,
                                                   Woc, boc, d_out, flags);
}